// Round 2
// baseline (643.265 us; speedup 1.0000x reference)
//
#include <hip/hip_runtime.h>

#define NN 100000
#define NE 1600000

// ---- degree count: one int atomic per edge (dst side, self-loops added later) ----
__global__ __launch_bounds__(256) void k_deg(const int* __restrict__ dst,
                                             int* __restrict__ deg) {
    int e = blockIdx.x * 256 + threadIdx.x;   // grid exactly NE threads
    atomicAdd(&deg[dst[e]], 1);
}

// ---- dinv = rsqrt(indeg + 1)  (in-place int -> float) ----
__global__ __launch_bounds__(256) void k_dinv(const int* __restrict__ degi,
                                              float* __restrict__ dinv) {
    int i = blockIdx.x * 256 + threadIdx.x;
    if (i < NN) {
        int c = degi[i];
        dinv[i] = rsqrtf((float)(c + 1));
    }
}

// ---- h = x @ W_conv : one node per thread, 64 f32 accumulators ----
__global__ __launch_bounds__(256) void k_gemm1(const float* __restrict__ x,
                                               const float* __restrict__ Wf,
                                               float* __restrict__ h) {
    int node = blockIdx.x * 256 + threadIdx.x;
    int nclamp = node < NN ? node : NN - 1;
    const float4* xr = (const float4*)(x + (size_t)nclamp * 128);
    float acc[64];
#pragma unroll
    for (int d = 0; d < 64; ++d) acc[d] = 0.f;

#pragma unroll 1
    for (int k0 = 0; k0 < 128; k0 += 8) {
        float4 u0 = xr[(k0 >> 2) + 0];
        float4 u1 = xr[(k0 >> 2) + 1];
        float xv[8] = {u0.x, u0.y, u0.z, u0.w, u1.x, u1.y, u1.z, u1.w};
#pragma unroll
        for (int kk = 0; kk < 8; ++kk) {
            const float* wrow = Wf + (k0 + kk) * 64;   // uniform address -> s_load
#pragma unroll
            for (int d = 0; d < 64; ++d) acc[d] = fmaf(xv[kk], wrow[d], acc[d]);
        }
    }
    if (node < NN) {
        float4* hr = (float4*)(h + (size_t)node * 64);
#pragma unroll
        for (int d0 = 0; d0 < 64; d0 += 4) {
            float4 o; o.x = acc[d0]; o.y = acc[d0 + 1]; o.z = acc[d0 + 2]; o.w = acc[d0 + 3];
            hr[d0 >> 2] = o;
        }
    }
}

// ---- edge scatter: one wave per edge, lane = hidden dim ----
__global__ __launch_bounds__(256) void k_scatter(const int* __restrict__ ei,
                                                 const float* __restrict__ dinv,
                                                 const float* __restrict__ h,
                                                 float* __restrict__ agg) {
    int t = blockIdx.x * 256 + threadIdx.x;   // grid exactly NE*64 threads
    int e = t >> 6;
    int d = t & 63;
    int s  = ei[e];
    int dt = ei[NE + e];
    float nrm = dinv[s] * dinv[dt];
    float hv = h[(size_t)s * 64 + d];
    atomicAdd(agg + (size_t)dt * 64 + d, nrm * hv);
}

// ---- epilogue: self-loop + bias + relu + @W_lin + bias ----
// blockIdx even/odd selects which 64-col half of the output row this block does.
__global__ __launch_bounds__(256) void k_epi(const float* __restrict__ agg,
                                             const float* __restrict__ h,
                                             const float* __restrict__ dinv,
                                             const float* __restrict__ b_conv,
                                             const float* __restrict__ W2f,
                                             const float* __restrict__ b_lin,
                                             float* __restrict__ out) {
    int node = (blockIdx.x >> 1) * 256 + threadIdx.x;
    int half = blockIdx.x & 1;                 // uniform
    int nclamp = node < NN ? node : NN - 1;
    float di = dinv[nclamp];
    float di2 = di * di;
    const float* ar = agg + (size_t)nclamp * 64;
    const float* hr = h + (size_t)nclamp * 64;

    float acc[64];
#pragma unroll
    for (int j = 0; j < 64; ++j) acc[j] = b_lin[half * 64 + j];  // uniform

#pragma unroll 1
    for (int k0 = 0; k0 < 64; k0 += 8) {
        float4 a0 = *(const float4*)(ar + k0);
        float4 a1 = *(const float4*)(ar + k0 + 4);
        float4 h0 = *(const float4*)(hr + k0);
        float4 h1 = *(const float4*)(hr + k0 + 4);
        float t[8];
        t[0] = a0.x + di2 * h0.x + b_conv[k0 + 0];
        t[1] = a0.y + di2 * h0.y + b_conv[k0 + 1];
        t[2] = a0.z + di2 * h0.z + b_conv[k0 + 2];
        t[3] = a0.w + di2 * h0.w + b_conv[k0 + 3];
        t[4] = a1.x + di2 * h1.x + b_conv[k0 + 4];
        t[5] = a1.y + di2 * h1.y + b_conv[k0 + 5];
        t[6] = a1.z + di2 * h1.z + b_conv[k0 + 6];
        t[7] = a1.w + di2 * h1.w + b_conv[k0 + 7];
#pragma unroll
        for (int kk = 0; kk < 8; ++kk) t[kk] = fmaxf(t[kk], 0.f);
#pragma unroll
        for (int kk = 0; kk < 8; ++kk) {
            const float* wrow = W2f + (k0 + kk) * 128 + half * 64;   // uniform
#pragma unroll
            for (int j = 0; j < 64; ++j) acc[j] = fmaf(t[kk], wrow[j], acc[j]);
        }
    }

    if (node < NN) {
        float4* orow = (float4*)(out + (size_t)node * 128 + half * 64);
#pragma unroll
        for (int j0 = 0; j0 < 64; j0 += 4) {
            float4 o; o.x = acc[j0]; o.y = acc[j0 + 1]; o.z = acc[j0 + 2]; o.w = acc[j0 + 3];
            orow[j0 >> 2] = o;
        }
    }
}

extern "C" void kernel_launch(void* const* d_in, const int* in_sizes, int n_in,
                              void* d_out, int out_size, void* d_ws, size_t ws_size,
                              hipStream_t stream) {
    const float* x  = (const float*)d_in[0];
    const int*   ei = (const int*)d_in[1];
    const float* Wc = (const float*)d_in[2];
    const float* bc = (const float*)d_in[3];
    const float* Wl = (const float*)d_in[4];
    const float* bl = (const float*)d_in[5];
    float* out = (float*)d_out;

    char* ws = (char*)d_ws;
    // layout (16B aligned): [deg/dinv: 400384][agg f32: 25.6MB][h f32: 25.6MB]
    float* dinv = (float*)ws;
    float* agg  = (float*)(ws + 400384);
    float* h    = (float*)(ws + 26000384);

    hipMemsetAsync(d_ws, 0, 26000384, stream);                       // deg + agg = 0
    k_deg<<<NE / 256, 256, 0, stream>>>(ei + NE, (int*)dinv);
    k_dinv<<<(NN + 255) / 256, 256, 0, stream>>>((const int*)dinv, dinv);
    k_gemm1<<<(NN + 255) / 256, 256, 0, stream>>>(x, Wc, h);
    k_scatter<<<(NE * 64) / 256, 256, 0, stream>>>(ei, dinv, h, agg);
    k_epi<<<2 * ((NN + 255) / 256), 256, 0, stream>>>(agg, h, dinv, bc, Wl, bl, out);
}

// Round 3
// 473.129 us; speedup vs baseline: 1.3596x; 1.3596x over previous
//
#include <hip/hip_runtime.h>
#include <hip/hip_bf16.h>

#define NN 100000
#define NE 1600000
#define NB 391   // ceil(NN/256)

typedef unsigned short ushort_t;

static __device__ __forceinline__ float bf2f(ushort_t u) {
    union { unsigned int i; float f; } c; c.i = ((unsigned int)u) << 16; return c.f;
}
static __device__ __forceinline__ ushort_t f2bf(float f) {
    union { __hip_bfloat16 b; ushort_t u; } c; c.b = __float2bfloat16(f); return c.u;
}

// ---- in-degree histogram: one int atomic per edge ----
__global__ __launch_bounds__(256) void k_hist(const int* __restrict__ dst,
                                              int* __restrict__ deg) {
    int e = blockIdx.x * 256 + threadIdx.x;   // grid exactly NE threads
    atomicAdd(&deg[dst[e]], 1);
}

// ---- per-block sums of deg ----
__global__ __launch_bounds__(256) void k_bsum(const int* __restrict__ deg,
                                              int* __restrict__ bsum) {
    __shared__ int s[256];
    int i = blockIdx.x * 256 + threadIdx.x;
    int v = i < NN ? deg[i] : 0;
    s[threadIdx.x] = v;
    __syncthreads();
#pragma unroll
    for (int o = 128; o > 0; o >>= 1) {
        if (threadIdx.x < o) s[threadIdx.x] += s[threadIdx.x + o];
        __syncthreads();
    }
    if (threadIdx.x == 0) bsum[blockIdx.x] = s[0];
}

// ---- exclusive scan of NB block sums (single block, 512 threads) ----
__global__ __launch_bounds__(512) void k_scanb(const int* __restrict__ bsum,
                                               int* __restrict__ boff) {
    __shared__ int s[512];
    int t = threadIdx.x;
    int v = t < NB ? bsum[t] : 0;
    s[t] = v;
    __syncthreads();
#pragma unroll
    for (int o = 1; o < 512; o <<= 1) {
        int x = (t >= o) ? s[t - o] : 0;
        __syncthreads();
        s[t] += x;
        __syncthreads();
    }
    if (t < NB) boff[t] = s[t] - v;   // exclusive
}

// ---- per-element exclusive offsets = block-local scan + block offset; also init cursor ----
__global__ __launch_bounds__(256) void k_off(const int* __restrict__ deg,
                                             const int* __restrict__ boff,
                                             int* __restrict__ offsets,
                                             int* __restrict__ cursor) {
    __shared__ int s[256];
    int t = threadIdx.x;
    int i = blockIdx.x * 256 + t;
    int v = i < NN ? deg[i] : 0;
    s[t] = v;
    __syncthreads();
#pragma unroll
    for (int o = 1; o < 256; o <<= 1) {
        int x = (t >= o) ? s[t - o] : 0;
        __syncthreads();
        s[t] += x;
        __syncthreads();
    }
    int excl = s[t] - v + boff[blockIdx.x];
    if (i < NN) { offsets[i] = excl; cursor[i] = excl; }
}

// ---- dinv = rsqrt(indeg + 1) ----
__global__ __launch_bounds__(256) void k_dinv(const int* __restrict__ deg,
                                              float* __restrict__ dinv) {
    int i = blockIdx.x * 256 + threadIdx.x;
    if (i < NN) dinv[i] = rsqrtf((float)(deg[i] + 1));
}

// ---- CSR fill: slot = cursor[dst]++, csr[slot] = src ----
__global__ __launch_bounds__(256) void k_fill(const int* __restrict__ ei,
                                              int* __restrict__ cursor,
                                              int* __restrict__ csr) {
    int e = blockIdx.x * 256 + threadIdx.x;   // grid exactly NE threads
    int s  = ei[e];
    int dt = ei[NE + e];
    int pos = atomicAdd(&cursor[dt], 1);
    csr[pos] = s;
}

// ---- h' = dinv[node] * (x @ W_conv), stored bf16 ----
__global__ __launch_bounds__(256) void k_gemm1(const float* __restrict__ x,
                                               const float* __restrict__ Wf,
                                               const float* __restrict__ dinv,
                                               ushort_t* __restrict__ hp) {
    int node = blockIdx.x * 256 + threadIdx.x;
    int nclamp = node < NN ? node : NN - 1;
    const float4* xr = (const float4*)(x + (size_t)nclamp * 128);
    float acc[64];
#pragma unroll
    for (int d = 0; d < 64; ++d) acc[d] = 0.f;

#pragma unroll 1
    for (int k0 = 0; k0 < 128; k0 += 8) {
        float4 u0 = xr[(k0 >> 2) + 0];
        float4 u1 = xr[(k0 >> 2) + 1];
        float xv[8] = {u0.x, u0.y, u0.z, u0.w, u1.x, u1.y, u1.z, u1.w};
#pragma unroll
        for (int kk = 0; kk < 8; ++kk) {
            const float* wrow = Wf + (k0 + kk) * 64;   // uniform address -> s_load
#pragma unroll
            for (int d = 0; d < 64; ++d) acc[d] = fmaf(xv[kk], wrow[d], acc[d]);
        }
    }
    if (node < NN) {
        float di = dinv[node];
        uint4* hr = (uint4*)(hp + (size_t)node * 64);
#pragma unroll
        for (int d0 = 0; d0 < 64; d0 += 8) {
            uint4 o;
            o.x = (unsigned)f2bf(di * acc[d0 + 0]) | ((unsigned)f2bf(di * acc[d0 + 1]) << 16);
            o.y = (unsigned)f2bf(di * acc[d0 + 2]) | ((unsigned)f2bf(di * acc[d0 + 3]) << 16);
            o.z = (unsigned)f2bf(di * acc[d0 + 4]) | ((unsigned)f2bf(di * acc[d0 + 5]) << 16);
            o.w = (unsigned)f2bf(di * acc[d0 + 6]) | ((unsigned)f2bf(di * acc[d0 + 7]) << 16);
            hr[d0 >> 3] = o;
        }
    }
}

// ---- gather-side aggregation: one wave per node, lane = dim ----
// a[n,d] = relu( dinv[n] * (sum_{src in in(n)} hp[src,d] + hp[n,d]) + b_conv[d] )
__global__ __launch_bounds__(256) void k_gather(const int* __restrict__ offsets,
                                                const int* __restrict__ deg,
                                                const int* __restrict__ csr,
                                                const float* __restrict__ dinv,
                                                const ushort_t* __restrict__ hp,
                                                const float* __restrict__ b_conv,
                                                float* __restrict__ a) {
    int node = (blockIdx.x * 256 + threadIdx.x) >> 6;   // grid exactly NN waves
    int lane = threadIdx.x & 63;
    int start = offsets[node];
    int cnt   = deg[node];

    float s0 = 0.f, s1 = 0.f, s2 = 0.f, s3 = 0.f;
#pragma unroll 1
    for (int j0 = 0; j0 < cnt; j0 += 64) {
        int m = cnt - j0; m = m < 64 ? m : 64;   // wave-uniform
        int col = 0;
        if (lane < m) col = csr[start + j0 + lane];
        int jj = 0;
#pragma unroll 1
        for (; jj + 4 <= m; jj += 4) {
            int c0 = __shfl(col, jj, 64);
            int c1 = __shfl(col, jj + 1, 64);
            int c2 = __shfl(col, jj + 2, 64);
            int c3 = __shfl(col, jj + 3, 64);
            float v0 = bf2f(hp[(size_t)c0 * 64 + lane]);
            float v1 = bf2f(hp[(size_t)c1 * 64 + lane]);
            float v2 = bf2f(hp[(size_t)c2 * 64 + lane]);
            float v3 = bf2f(hp[(size_t)c3 * 64 + lane]);
            s0 += v0; s1 += v1; s2 += v2; s3 += v3;
        }
        for (; jj < m; ++jj) {
            int c = __shfl(col, jj, 64);
            s0 += bf2f(hp[(size_t)c * 64 + lane]);
        }
    }
    float acc = (s0 + s1) + (s2 + s3);
    acc += bf2f(hp[(size_t)node * 64 + lane]);          // self-loop
    float v = dinv[node] * acc + b_conv[lane];
    a[(size_t)node * 64 + lane] = fmaxf(v, 0.f);
}

// ---- epilogue GEMM: out = a @ W_lin + b_lin ----
__global__ __launch_bounds__(256) void k_epi(const float* __restrict__ a,
                                             const float* __restrict__ W2f,
                                             const float* __restrict__ b_lin,
                                             float* __restrict__ out) {
    int node = (blockIdx.x >> 1) * 256 + threadIdx.x;
    int half = blockIdx.x & 1;                 // uniform
    int nclamp = node < NN ? node : NN - 1;
    const float* ar = a + (size_t)nclamp * 64;

    float acc[64];
#pragma unroll
    for (int j = 0; j < 64; ++j) acc[j] = b_lin[half * 64 + j];  // uniform

#pragma unroll 1
    for (int k0 = 0; k0 < 64; k0 += 8) {
        float4 a0 = *(const float4*)(ar + k0);
        float4 a1 = *(const float4*)(ar + k0 + 4);
        float t[8] = {a0.x, a0.y, a0.z, a0.w, a1.x, a1.y, a1.z, a1.w};
#pragma unroll
        for (int kk = 0; kk < 8; ++kk) {
            const float* wrow = W2f + (k0 + kk) * 128 + half * 64;   // uniform
#pragma unroll
            for (int j = 0; j < 64; ++j) acc[j] = fmaf(t[kk], wrow[j], acc[j]);
        }
    }

    if (node < NN) {
        float4* orow = (float4*)(out + (size_t)node * 128 + half * 64);
#pragma unroll
        for (int j0 = 0; j0 < 64; j0 += 4) {
            float4 o; o.x = acc[j0]; o.y = acc[j0 + 1]; o.z = acc[j0 + 2]; o.w = acc[j0 + 3];
            orow[j0 >> 2] = o;
        }
    }
}

extern "C" void kernel_launch(void* const* d_in, const int* in_sizes, int n_in,
                              void* d_out, int out_size, void* d_ws, size_t ws_size,
                              hipStream_t stream) {
    const float* x  = (const float*)d_in[0];
    const int*   ei = (const int*)d_in[1];
    const float* Wc = (const float*)d_in[2];
    const float* bc = (const float*)d_in[3];
    const float* Wl = (const float*)d_in[4];
    const float* bl = (const float*)d_in[5];
    float* out = (float*)d_out;

    char* ws = (char*)d_ws;
    // layout (128B aligned), total 46.4 MB:
    int*      deg     = (int*)(ws + 0);          // 400384
    int*      offsets = (int*)(ws + 400384);     // 400384
    int*      cursor  = (int*)(ws + 800768);     // 400384
    float*    dinv    = (float*)(ws + 1201152);  // 400384
    int*      bsum    = (int*)(ws + 1601536);    // 2048
    int*      boff    = (int*)(ws + 1603584);    // 2048
    int*      csr     = (int*)(ws + 1605632);    // 6400000
    ushort_t* hp      = (ushort_t*)(ws + 8005632);   // 12800000 (bf16)
    float*    a       = (float*)(ws + 20805632);     // 25600000

    hipMemsetAsync(deg, 0, 400384, stream);
    k_hist <<<NE / 256, 256, 0, stream>>>(ei + NE, deg);
    k_bsum <<<NB, 256, 0, stream>>>(deg, bsum);
    k_scanb<<<1, 512, 0, stream>>>(bsum, boff);
    k_off  <<<NB, 256, 0, stream>>>(deg, boff, offsets, cursor);
    k_dinv <<<NB, 256, 0, stream>>>(deg, dinv);
    k_gemm1<<<NB, 256, 0, stream>>>(x, Wc, dinv, hp);
    k_fill <<<NE / 256, 256, 0, stream>>>(ei, cursor, csr);
    k_gather<<<NN * 64 / 256, 256, 0, stream>>>(offsets, deg, csr, dinv, hp, bc, a);
    k_epi  <<<2 * NB, 256, 0, stream>>>(a, Wl, bl, out);
}